// Round 2
// baseline (317.223 us; speedup 1.0000x reference)
//
#include <hip/hip_runtime.h>

// Output = conv1x1(x, refine_w, refine_b). Everything else in the reference is
// dead code: `_dead` is unused, and x_back == x exactly (permutation followed
// by its argsort-inverse).
//
// x: (8, 64, 256, 256) fp32, refine_w: (64, 64) [o-major], refine_b: (64,)
// out[b,o,h,w] = sum_c w[o,c] * x[b,c,h,w] + b[o]
//
// v3: round-1 counters showed 72% stall with VALUBusy == pure-FMA floor ->
// load latency fully exposed once per c-chunk (loads for chunk k+1 only issue
// after chunk k's FMAs). Fix: explicit register double-buffer. Chunk k+1's
// four float4 loads are issued BEFORE chunk k's FMAs consume stg[cur], so the
// compiler emits s_waitcnt vmcnt(4) and the ~600-1200 cyc latency overlaps
// 512 cycles of FMA issue per wave x 16 waves/CU.
// All stg/acc indices are compile-time (full unroll) -- runtime-indexed
// ext_vector arrays go to scratch (rule #20).

constexpr int  C     = 64;
constexpr long HW    = 65536;       // 256*256
constexpr long NPIX  = 8L * HW;     // 524288 pixels
constexpr int  P     = 4;           // pixels per thread (float4)
constexpr int  OG    = 4;           // o-groups (one per wave)
constexpr int  OPT   = C / OG;      // 16 output channels per thread
constexpr int  CHUNK = 4;           // c-channels staged per pipeline stage
constexpr int  NCB   = C / CHUNK;   // 16 chunks
constexpr int  PIX_PER_BLOCK = 64 * P;  // 256

typedef float f4 __attribute__((ext_vector_type(4)));

__global__ __launch_bounds__(256, 4) void conv1x1_refine_kernel(
    const float* __restrict__ x,
    const float* __restrict__ w,     // (64,64) o-major
    const float* __restrict__ bias,  // (64,)
    float* __restrict__ out)
{
    const int t  = threadIdx.x;
    const int q  = t & 63;                                   // pixel-quad index
    const int og = __builtin_amdgcn_readfirstlane(t >> 6);   // wave-uniform -> SGPR

    const long pix = (long)blockIdx.x * PIX_PER_BLOCK + (long)q * P;
    const long b   = pix >> 16;            // blocks never straddle a batch
    const long hw  = pix & (HW - 1);

    const float* xb = x + b * ((long)C * HW) + hw;
    const float* wg = w + og * OPT * C;    // this wave's 16 rows of w
    float*       ob = out + b * ((long)C * HW) + (long)og * OPT * HW + hw;

    f4 acc[OPT];
#pragma unroll
    for (int o = 0; o < OPT; ++o) {
        const float bv = bias[og * OPT + o];   // uniform -> s_load
        acc[o] = (f4){bv, bv, bv, bv};
    }

    // Register double-buffer over c-chunks: issue chunk cb+1's loads before
    // consuming chunk cb. cur/nxt are compile-time constants after unroll.
    f4 stg[2][CHUNK];
#pragma unroll
    for (int k = 0; k < CHUNK; ++k)
        stg[0][k] = *reinterpret_cast<const f4*>(xb + (long)k * HW);

#pragma unroll
    for (int cb = 0; cb < NCB; ++cb) {
        const int cur = cb & 1;
        const int nxt = cur ^ 1;

        if (cb + 1 < NCB) {
#pragma unroll
            for (int k = 0; k < CHUNK; ++k)
                stg[nxt][k] = *reinterpret_cast<const f4*>(
                    xb + (long)((cb + 1) * CHUNK + k) * HW);
        }

#pragma unroll
        for (int k = 0; k < CHUNK; ++k) {
            const int c  = cb * CHUNK + k;
            const f4 xv  = stg[cur][k];
#pragma unroll
            for (int o = 0; o < OPT; ++o) {
                const float wv = wg[o * C + c];  // uniform -> s_load operand
                acc[o].x = fmaf(wv, xv.x, acc[o].x);
                acc[o].y = fmaf(wv, xv.y, acc[o].y);
                acc[o].z = fmaf(wv, xv.z, acc[o].z);
                acc[o].w = fmaf(wv, xv.w, acc[o].w);
            }
        }
    }

    // Streamed output, never re-read: nontemporal keeps x resident in LLC.
#pragma unroll
    for (int o = 0; o < OPT; ++o)
        __builtin_nontemporal_store(acc[o], reinterpret_cast<f4*>(ob + (long)o * HW));
}

extern "C" void kernel_launch(void* const* d_in, const int* in_sizes, int n_in,
                              void* d_out, int out_size, void* d_ws, size_t ws_size,
                              hipStream_t stream)
{
    const float* x  = (const float*)d_in[0];   // x
    const float* rw = (const float*)d_in[11];  // refine_w
    const float* rb = (const float*)d_in[12];  // refine_b
    float* out = (float*)d_out;

    const int threads = 256;
    const int blocks  = (int)(NPIX / PIX_PER_BLOCK);  // 2048
    hipLaunchKernelGGL(conv1x1_refine_kernel, dim3(blocks), dim3(threads), 0, stream,
                       x, rw, rb, out);
}